// Round 13
// baseline (410.467 us; speedup 1.0000x reference)
//
#include <hip/hip_runtime.h>

typedef float f32x4 __attribute__((ext_vector_type(4)));
typedef short bf16x8 __attribute__((ext_vector_type(8)));

__device__ __forceinline__ unsigned short f2bf(float f) {
  unsigned int u = __float_as_uint(f);
  u += 0x7FFFu + ((u >> 16) & 1u);  // RNE
  return (unsigned short)(u >> 16);
}
__device__ __forceinline__ float bflo(unsigned int u) {  // low bf16 -> f32
  return __uint_as_float(u << 16);
}
__device__ __forceinline__ float bfhi(unsigned int u) {  // high bf16 -> f32
  return __uint_as_float(u & 0xFFFF0000u);
}

// ---------------- build node -> compact id map ----------------
__global__ void k_build_map(const int* __restrict__ tri_nodes, int* __restrict__ map,
                            int* __restrict__ uniq, int* __restrict__ counter, int n) {
  int i = blockIdx.x * blockDim.x + threadIdx.x;
  if (i >= n) return;
  int node = tri_nodes[i];
  int old = atomicCAS(&map[node], -1, -2);
  if (old == -1) {
    int mid = atomicAdd(counter, 1);
    uniq[mid] = node;
    map[node] = mid;
  }
}

// ---------------- ONE E-pass: count per comb + compact needed edges ----------------
// Replaces the old separate k_count and k_scatter E-sweeps (each 19 MB + 445K
// random map probes). c_pk gets (comb, src) pairs in arbitrary order.
__global__ void k_compact(const int* __restrict__ esrc, const int* __restrict__ edst,
                          const int* __restrict__ erel, const int* __restrict__ map,
                          int* __restrict__ cnt_c, int* __restrict__ ec,
                          int2* __restrict__ c_pk, int E) {
  int i = blockIdx.x * blockDim.x + threadIdx.x;
  if (i >= E) return;
  int mid = map[edst[i]];
  if (mid >= 0) {
    int comb = mid * 8 + erel[i];
    atomicAdd(&cnt_c[comb], 1);
    int pos = atomicAdd(ec, 1);  // wave-aggregated by compiler (G12)
    c_pk[pos] = make_int2(comb, esrc[i]);
  }
}

// ---------------- hierarchical exclusive scan over M=262144 entries ----------------
__global__ __launch_bounds__(256) void k_scan_s1(const int* __restrict__ cnt_c,
                                                 int* __restrict__ bsum) {
  __shared__ int sh[256];
  int tid = threadIdx.x;
  int base = blockIdx.x * 1024 + tid * 4;
  int s = cnt_c[base] + cnt_c[base + 1] + cnt_c[base + 2] + cnt_c[base + 3];
  sh[tid] = s;
  __syncthreads();
  for (int o = 1; o < 256; o <<= 1) {
    int x = (tid >= o) ? sh[tid - o] : 0;
    __syncthreads();
    sh[tid] += x;
    __syncthreads();
  }
  if (tid == 255) bsum[blockIdx.x] = sh[255];
}
__global__ __launch_bounds__(256) void k_scan_s2(int* __restrict__ bsum,
                                                 int* __restrict__ seg_start, int M) {
  __shared__ int sh[256];
  int tid = threadIdx.x;
  int v = bsum[tid];
  sh[tid] = v;
  __syncthreads();
  for (int o = 1; o < 256; o <<= 1) {
    int x = (tid >= o) ? sh[tid - o] : 0;
    __syncthreads();
    sh[tid] += x;
    __syncthreads();
  }
  bsum[tid] = sh[tid] - v;  // exclusive
  if (tid == 255) seg_start[M] = sh[255];
}
__global__ __launch_bounds__(256) void k_scan_s3(const int* __restrict__ cnt_c,
                                                 const int* __restrict__ bsum,
                                                 int* __restrict__ seg_start,
                                                 int* __restrict__ seg_ofs) {
  __shared__ int sh[256];
  int tid = threadIdx.x;
  int base = blockIdx.x * 1024 + tid * 4;
  int c0 = cnt_c[base], c1 = cnt_c[base + 1], c2 = cnt_c[base + 2], c3 = cnt_c[base + 3];
  int s = c0 + c1 + c2 + c3;
  sh[tid] = s;
  __syncthreads();
  for (int o = 1; o < 256; o <<= 1) {
    int x = (tid >= o) ? sh[tid - o] : 0;
    __syncthreads();
    sh[tid] += x;
    __syncthreads();
  }
  int run = bsum[blockIdx.x] + sh[tid] - s;
  seg_start[base] = run; seg_ofs[base] = run; run += c0;
  seg_start[base + 1] = run; seg_ofs[base + 1] = run; run += c1;
  seg_start[base + 2] = run; seg_ofs[base + 2] = run; run += c2;
  seg_start[base + 3] = run; seg_ofs[base + 3] = run;
}

// ---------------- scatter compacted pairs into comb-sorted order ----------------
__global__ void k_scatter2(const int2* __restrict__ c_pk, const int* __restrict__ ec,
                           int* __restrict__ seg_ofs, int* __restrict__ s_src) {
  int i = blockIdx.x * blockDim.x + threadIdx.x;
  if (i >= *ec) return;
  int2 p = c_pk[i];
  int pos = atomicAdd(&seg_ofs[p.x], 1);
  s_src[pos] = p.y;
}

// ---------------- W -> bf16 FRAGMENT-MAJOR: Wf[((r*16+ku)*128+col)*8+j] = W[r][ku*8+j][col]
__global__ void k_cvt_w(const float* __restrict__ W_rel, const float* __restrict__ W_self,
                        unsigned short* __restrict__ Wf) {
  int i = blockIdx.x * 256 + threadIdx.x;  // over 9*16384 bf16 elements
  if (i >= 9 * 16384) return;
  int j = i & 7;
  int tmp = i >> 3;
  int col = tmp & 127;
  int ku = (tmp >> 7) & 15;
  int r = tmp >> 11;
  int d = ku * 8 + j;
  float v = (r < 8) ? W_rel[r * 16384 + d * 128 + col] : W_self[d * 128 + col];
  Wf[i] = f2bf(v);
}

// ---------------- X -> bf16 (ws-gated): halves gather bytes ----------------
__global__ void k_cvt_x(const float* __restrict__ X, unsigned short* __restrict__ X16,
                        int total8) {
  int i = blockIdx.x * 256 + threadIdx.x;  // one thread per 8 elements
  if (i >= total8) return;
  const float4* s = (const float4*)(X + (size_t)i * 8);
  float4 v0 = s[0], v1 = s[1];
  uint4 p;
  p.x = (unsigned int)f2bf(v0.x) | ((unsigned int)f2bf(v0.y) << 16);
  p.y = (unsigned int)f2bf(v0.z) | ((unsigned int)f2bf(v0.w) << 16);
  p.z = (unsigned int)f2bf(v1.x) | ((unsigned int)f2bf(v1.y) << 16);
  p.w = (unsigned int)f2bf(v1.z) | ((unsigned int)f2bf(v1.w) << 16);
  ((uint4*)X16)[i] = p;
}

// ---------------- fused RGCN GEMM on matrix cores (unchanged from r12) ----------------
template <int XMODE>
__global__ __launch_bounds__(256) void k_fused(
    const float* __restrict__ X, const unsigned short* __restrict__ X16,
    const unsigned short* __restrict__ Wf, const float* __restrict__ bvec,
    const int* __restrict__ uniq, const int* __restrict__ counter,
    const int* __restrict__ seg_start, const int* __restrict__ s_src,
    float* __restrict__ Hacc) {
  __shared__ __align__(16) unsigned short a_lds[16 * 128];  // 4 KB, swizzled

  int nm = *counter;
  int mid0 = blockIdx.x * 16;
  if (mid0 >= nm) return;

  int t = threadIdx.x;
  int er = t >> 4, seg = t & 15;
  int lane = t & 63, l15 = lane & 15, lg = lane >> 4;
  int wc = t >> 6;
  int mid = mid0 + er;

  f32x4 acc[2];
  {
    f32x4 z = {0.f, 0.f, 0.f, 0.f};
    acc[0] = z; acc[1] = z;
  }

  for (int r = 0; r < 9; ++r) {
    __syncthreads();

    {  // stage A row er chunk seg (8 values)
      float aa[8];
#pragma unroll
      for (int q = 0; q < 8; ++q) aa[q] = 0.f;
      if (r < 8) {
        int comb = mid * 8 + r;
        int s0 = seg_start[comb], s1 = seg_start[comb + 1];
        int cnt = s1 - s0;
        int e = s0;
        if (XMODE == 0) {
          for (; e + 2 <= s1; e += 2) {
            int i0 = s_src[e], i1 = s_src[e + 1];
            const float4* x0 = (const float4*)(X + (size_t)i0 * 128) + seg * 2;
            const float4* x1 = (const float4*)(X + (size_t)i1 * 128) + seg * 2;
            float4 a0 = x0[0], a1 = x0[1], b0 = x1[0], b1 = x1[1];
            aa[0] += a0.x + b0.x; aa[1] += a0.y + b0.y;
            aa[2] += a0.z + b0.z; aa[3] += a0.w + b0.w;
            aa[4] += a1.x + b1.x; aa[5] += a1.y + b1.y;
            aa[6] += a1.z + b1.z; aa[7] += a1.w + b1.w;
          }
          if (e < s1) {
            const float4* x0 = (const float4*)(X + (size_t)s_src[e] * 128) + seg * 2;
            float4 a0 = x0[0], a1 = x0[1];
            aa[0] += a0.x; aa[1] += a0.y; aa[2] += a0.z; aa[3] += a0.w;
            aa[4] += a1.x; aa[5] += a1.y; aa[6] += a1.z; aa[7] += a1.w;
          }
        } else {
          for (; e + 2 <= s1; e += 2) {
            int i0 = s_src[e], i1 = s_src[e + 1];
            uint4 u = *(const uint4*)(X16 + (size_t)i0 * 128 + seg * 8);
            uint4 v = *(const uint4*)(X16 + (size_t)i1 * 128 + seg * 8);
            aa[0] += bflo(u.x) + bflo(v.x); aa[1] += bfhi(u.x) + bfhi(v.x);
            aa[2] += bflo(u.y) + bflo(v.y); aa[3] += bfhi(u.y) + bfhi(v.y);
            aa[4] += bflo(u.z) + bflo(v.z); aa[5] += bfhi(u.z) + bfhi(v.z);
            aa[6] += bflo(u.w) + bflo(v.w); aa[7] += bfhi(u.w) + bfhi(v.w);
          }
          if (e < s1) {
            uint4 u = *(const uint4*)(X16 + (size_t)s_src[e] * 128 + seg * 8);
            aa[0] += bflo(u.x); aa[1] += bfhi(u.x);
            aa[2] += bflo(u.y); aa[3] += bfhi(u.y);
            aa[4] += bflo(u.z); aa[5] += bfhi(u.z);
            aa[6] += bflo(u.w); aa[7] += bfhi(u.w);
          }
        }
        if (cnt > 1) {
          float sc = 1.0f / (float)cnt;
#pragma unroll
          for (int q = 0; q < 8; ++q) aa[q] *= sc;
        }
      } else if (mid < nm) {
        if (XMODE == 0) {
          const float4* xr = (const float4*)(X + (size_t)uniq[mid] * 128) + seg * 2;
          float4 v0 = xr[0], v1 = xr[1];
          aa[0] = v0.x; aa[1] = v0.y; aa[2] = v0.z; aa[3] = v0.w;
          aa[4] = v1.x; aa[5] = v1.y; aa[6] = v1.z; aa[7] = v1.w;
        } else {
          uint4 u = *(const uint4*)(X16 + (size_t)uniq[mid] * 128 + seg * 8);
          aa[0] = bflo(u.x); aa[1] = bfhi(u.x);
          aa[2] = bflo(u.y); aa[3] = bfhi(u.y);
          aa[4] = bflo(u.z); aa[5] = bfhi(u.z);
          aa[6] = bflo(u.w); aa[7] = bfhi(u.w);
        }
      }
      uint4 p;
      p.x = (unsigned int)f2bf(aa[0]) | ((unsigned int)f2bf(aa[1]) << 16);
      p.y = (unsigned int)f2bf(aa[2]) | ((unsigned int)f2bf(aa[3]) << 16);
      p.z = (unsigned int)f2bf(aa[4]) | ((unsigned int)f2bf(aa[5]) << 16);
      p.w = (unsigned int)f2bf(aa[6]) | ((unsigned int)f2bf(aa[7]) << 16);
      *(uint4*)&a_lds[(((er * 16 + seg) ^ (er & 7)) * 8)] = p;
    }
    __syncthreads();

    const unsigned short* wf = Wf + r * 16384;
#pragma unroll
    for (int kb = 0; kb < 4; ++kb) {
      int ku = kb * 4 + lg;
      bf16x8 af = *(const bf16x8*)&a_lds[((l15 * 16 + ku) ^ (l15 & 7)) * 8];
#pragma unroll
      for (int n = 0; n < 2; ++n) {
        int col = wc * 32 + n * 16 + l15;
        bf16x8 bfr = *(const bf16x8*)(wf + ((size_t)(ku * 128 + col)) * 8);
        acc[n] = __builtin_amdgcn_mfma_f32_16x16x32_bf16(af, bfr, acc[n], 0, 0, 0);
      }
    }
  }

#pragma unroll
  for (int n = 0; n < 2; ++n) {
    int col = wc * 32 + n * 16 + l15;
    float bv = bvec[col];
#pragma unroll
    for (int q = 0; q < 4; ++q) {
      int row = mid0 + lg * 4 + q;
      float v = acc[n][q] + bv;
      Hacc[(size_t)row * 128 + col] = v > 0.f ? v : 0.f;
    }
  }
}

// ---------------- DistMult score: one wave per triple ----------------
__global__ void k_score(const float* __restrict__ H, const int* __restrict__ map,
                        const float* __restrict__ rel_emb, const int* __restrict__ tri_nodes,
                        const int* __restrict__ tri_rel, float* __restrict__ out, int B) {
  int w = (blockIdx.x * blockDim.x + threadIdx.x) >> 6;
  int lane = threadIdx.x & 63;
  if (w >= B) return;
  int s = map[tri_nodes[w * 2]];
  int o = map[tri_nodes[w * 2 + 1]];
  const float* hs = H + (size_t)s * 128;
  const float* ho = H + (size_t)o * 128;
  const float* rr = rel_emb + (size_t)tri_rel[w] * 128;
  float p = hs[lane] * ho[lane] * rr[lane] + hs[lane + 64] * ho[lane + 64] * rr[lane + 64];
#pragma unroll
  for (int ofs = 32; ofs > 0; ofs >>= 1) p += __shfl_down(p, ofs);
  if (lane == 0) out[w] = p;
}

extern "C" void kernel_launch(void* const* d_in, const int* in_sizes, int n_in,
                              void* d_out, int out_size, void* d_ws, size_t ws_size,
                              hipStream_t stream) {
  const float* X       = (const float*)d_in[0];
  const float* W_rel   = (const float*)d_in[1];
  const float* W_self  = (const float*)d_in[2];
  const float* bvec    = (const float*)d_in[3];
  const float* rel_emb = (const float*)d_in[4];
  const int* edge_src  = (const int*)d_in[5];
  const int* edge_dst  = (const int*)d_in[6];
  const int* edge_rel  = (const int*)d_in[7];
  const int* tri_nodes = (const int*)d_in[8];
  const int* tri_rel   = (const int*)d_in[9];

  int N  = in_sizes[0] / 128;   // 100000
  int E  = in_sizes[5];         // 1600000
  int nt = in_sizes[8];         // 2*B = 32768
  int B  = in_sizes[9];         // 16384
  int M  = nt * 8;              // 262144 combs

  char* ws = (char*)d_ws;
  int* map       = (int*)ws;                 // N
  int* counter   = map + N;                  // [0]=nm, [1]=ec (+pad 64)
  int* uniq      = counter + 64;             // nt
  int* cnt_c     = uniq + nt;                // M  (reused as Wf after scan_s3)
  int* seg_start = cnt_c + M;                // M+1 (+pad 64)
  int* seg_ofs   = seg_start + M + 64;       // M
  int* bsum      = seg_ofs + M;              // 256
  int* s_src     = bsum + 256;               // E
  float* Hacc    = (float*)(s_src + E);      // nt*128 floats
  unsigned short* Wf  = (unsigned short*)cnt_c;  // aliases dead cnt_c
  unsigned short* X16 = (unsigned short*)(Hacc + (size_t)nt * 128);  // N*128 bf16
  size_t need_big = ((char*)(X16 + (size_t)N * 128)) - ws;  // ~52.5 MB (proven r12)
  bool bigws = ws_size >= need_big;
  // c_pk (E int2 = 12.8 MB) aliases X16 (25.6 MB, written later) in bigws mode,
  // or Hacc (16.8 MB, written later) otherwise. Both are dead at c_pk's lifetime.
  int2* c_pk = bigws ? (int2*)X16 : (int2*)Hacc;

  hipMemsetAsync(map, 0xFF, (size_t)N * 4, stream);  // -1
  hipMemsetAsync(counter, 0, 64 * 4, stream);
  hipMemsetAsync(cnt_c, 0, (size_t)M * 4, stream);

  int eblocks = (E + 255) / 256;
  k_build_map<<<(nt + 255) / 256, 256, 0, stream>>>(tri_nodes, map, uniq, counter, nt);
  k_compact<<<eblocks, 256, 0, stream>>>(edge_src, edge_dst, edge_rel, map, cnt_c,
                                         counter + 1, c_pk, E);
  k_scan_s1<<<256, 256, 0, stream>>>(cnt_c, bsum);
  k_scan_s2<<<1, 256, 0, stream>>>(bsum, seg_start, M);
  k_scan_s3<<<256, 256, 0, stream>>>(cnt_c, bsum, seg_start, seg_ofs);
  // cnt_c dead from here; overwrite with bf16 fragment-major weights
  k_cvt_w<<<(9 * 16384 + 255) / 256, 256, 0, stream>>>(W_rel, W_self, Wf);
  k_scatter2<<<eblocks, 256, 0, stream>>>(c_pk, counter + 1, seg_ofs, s_src);
  // c_pk dead from here
  if (bigws) {
    k_cvt_x<<<(N * 16 + 255) / 256, 256, 0, stream>>>(X, X16, N * 16);
    k_fused<1><<<nt / 16, 256, 0, stream>>>(X, X16, Wf, bvec, uniq, counter,
                                            seg_start, s_src, Hacc);
  } else {
    k_fused<0><<<nt / 16, 256, 0, stream>>>(X, X16, Wf, bvec, uniq, counter,
                                            seg_start, s_src, Hacc);
  }
  k_score<<<(B * 64 + 255) / 256, 256, 0, stream>>>(Hacc, map, rel_emb, tri_nodes,
                                                    tri_rel, (float*)d_out, B);
}

// Round 14
// 194.783 us; speedup vs baseline: 2.1073x; 2.1073x over previous
//
#include <hip/hip_runtime.h>

typedef float f32x4 __attribute__((ext_vector_type(4)));
typedef short bf16x8 __attribute__((ext_vector_type(8)));

__device__ __forceinline__ unsigned short f2bf(float f) {
  unsigned int u = __float_as_uint(f);
  u += 0x7FFFu + ((u >> 16) & 1u);  // RNE
  return (unsigned short)(u >> 16);
}
__device__ __forceinline__ float bflo(unsigned int u) {  // low bf16 -> f32
  return __uint_as_float(u << 16);
}
__device__ __forceinline__ float bfhi(unsigned int u) {  // high bf16 -> f32
  return __uint_as_float(u & 0xFFFF0000u);
}

// ---------------- build node -> compact id map ----------------
__global__ void k_build_map(const int* __restrict__ tri_nodes, int* __restrict__ map,
                            int* __restrict__ uniq, int* __restrict__ counter, int n) {
  int i = blockIdx.x * blockDim.x + threadIdx.x;
  if (i >= n) return;
  int node = tri_nodes[i];
  int old = atomicCAS(&map[node], -1, -2);
  if (old == -1) {
    int mid = atomicAdd(counter, 1);
    uniq[mid] = node;
    map[node] = mid;
  }
}

// ---------------- ONE E-pass: count per comb + compact needed edges ----------------
// Position allocation is BLOCK-AGGREGATED (round-3 pattern): ballot ranks in
// wave, LDS prefix over 4 waves, ONE returning atomicAdd per block. Round-13's
// per-thread atomicAdd(ec,1) on one address cost 291us in XCD ping-pong.
__global__ __launch_bounds__(256) void k_compact(
    const int* __restrict__ esrc, const int* __restrict__ edst,
    const int* __restrict__ erel, const int* __restrict__ map,
    int* __restrict__ cnt_c, int* __restrict__ ec,
    int2* __restrict__ c_pk, int E) {
  __shared__ int wbase[4];
  __shared__ int blockbase;
  int t = threadIdx.x;
  int i = blockIdx.x * 256 + t;
  bool valid = false;
  int comb = 0, src = 0;
  if (i < E) {
    int mid = map[edst[i]];
    if (mid >= 0) {
      valid = true;
      comb = mid * 8 + erel[i];
      src = esrc[i];
      atomicAdd(&cnt_c[comb], 1);  // 262K distinct addresses: low contention
    }
  }
  unsigned long long m = __ballot(valid);
  int lane = t & 63, wid = t >> 6;
  int rank = (int)__popcll(m & ((1ull << lane) - 1ull));
  if (lane == 0) wbase[wid] = (int)__popcll(m);
  __syncthreads();
  if (t == 0) {
    int c0 = wbase[0], c1 = wbase[1], c2 = wbase[2], c3 = wbase[3];
    int total = c0 + c1 + c2 + c3;
    blockbase = total ? atomicAdd(ec, total) : 0;  // ONE atomic per block
    wbase[0] = 0; wbase[1] = c0; wbase[2] = c0 + c1; wbase[3] = c0 + c1 + c2;
  }
  __syncthreads();
  if (valid) c_pk[blockbase + wbase[wid] + rank] = make_int2(comb, src);
}

// ---------------- hierarchical exclusive scan over M=262144 entries ----------------
__global__ __launch_bounds__(256) void k_scan_s1(const int* __restrict__ cnt_c,
                                                 int* __restrict__ bsum) {
  __shared__ int sh[256];
  int tid = threadIdx.x;
  int base = blockIdx.x * 1024 + tid * 4;
  int s = cnt_c[base] + cnt_c[base + 1] + cnt_c[base + 2] + cnt_c[base + 3];
  sh[tid] = s;
  __syncthreads();
  for (int o = 1; o < 256; o <<= 1) {
    int x = (tid >= o) ? sh[tid - o] : 0;
    __syncthreads();
    sh[tid] += x;
    __syncthreads();
  }
  if (tid == 255) bsum[blockIdx.x] = sh[255];
}
__global__ __launch_bounds__(256) void k_scan_s2(int* __restrict__ bsum,
                                                 int* __restrict__ seg_start, int M) {
  __shared__ int sh[256];
  int tid = threadIdx.x;
  int v = bsum[tid];
  sh[tid] = v;
  __syncthreads();
  for (int o = 1; o < 256; o <<= 1) {
    int x = (tid >= o) ? sh[tid - o] : 0;
    __syncthreads();
    sh[tid] += x;
    __syncthreads();
  }
  bsum[tid] = sh[tid] - v;  // exclusive
  if (tid == 255) seg_start[M] = sh[255];
}
__global__ __launch_bounds__(256) void k_scan_s3(const int* __restrict__ cnt_c,
                                                 const int* __restrict__ bsum,
                                                 int* __restrict__ seg_start,
                                                 int* __restrict__ seg_ofs) {
  __shared__ int sh[256];
  int tid = threadIdx.x;
  int base = blockIdx.x * 1024 + tid * 4;
  int c0 = cnt_c[base], c1 = cnt_c[base + 1], c2 = cnt_c[base + 2], c3 = cnt_c[base + 3];
  int s = c0 + c1 + c2 + c3;
  sh[tid] = s;
  __syncthreads();
  for (int o = 1; o < 256; o <<= 1) {
    int x = (tid >= o) ? sh[tid - o] : 0;
    __syncthreads();
    sh[tid] += x;
    __syncthreads();
  }
  int run = bsum[blockIdx.x] + sh[tid] - s;
  seg_start[base] = run; seg_ofs[base] = run; run += c0;
  seg_start[base + 1] = run; seg_ofs[base + 1] = run; run += c1;
  seg_start[base + 2] = run; seg_ofs[base + 2] = run; run += c2;
  seg_start[base + 3] = run; seg_ofs[base + 3] = run;
}

// ---------------- scatter compacted pairs into comb-sorted order ----------------
__global__ void k_scatter2(const int2* __restrict__ c_pk, const int* __restrict__ ec,
                           int* __restrict__ seg_ofs, int* __restrict__ s_src) {
  int i = blockIdx.x * blockDim.x + threadIdx.x;
  if (i >= *ec) return;
  int2 p = c_pk[i];
  int pos = atomicAdd(&seg_ofs[p.x], 1);
  s_src[pos] = p.y;
}

// ---------------- W -> bf16 FRAGMENT-MAJOR: Wf[((r*16+ku)*128+col)*8+j] = W[r][ku*8+j][col]
__global__ void k_cvt_w(const float* __restrict__ W_rel, const float* __restrict__ W_self,
                        unsigned short* __restrict__ Wf) {
  int i = blockIdx.x * 256 + threadIdx.x;  // over 9*16384 bf16 elements
  if (i >= 9 * 16384) return;
  int j = i & 7;
  int tmp = i >> 3;
  int col = tmp & 127;
  int ku = (tmp >> 7) & 15;
  int r = tmp >> 11;
  int d = ku * 8 + j;
  float v = (r < 8) ? W_rel[r * 16384 + d * 128 + col] : W_self[d * 128 + col];
  Wf[i] = f2bf(v);
}

// ---------------- X -> bf16 (ws-gated): halves gather bytes ----------------
__global__ void k_cvt_x(const float* __restrict__ X, unsigned short* __restrict__ X16,
                        int total8) {
  int i = blockIdx.x * 256 + threadIdx.x;  // one thread per 8 elements
  if (i >= total8) return;
  const float4* s = (const float4*)(X + (size_t)i * 8);
  float4 v0 = s[0], v1 = s[1];
  uint4 p;
  p.x = (unsigned int)f2bf(v0.x) | ((unsigned int)f2bf(v0.y) << 16);
  p.y = (unsigned int)f2bf(v0.z) | ((unsigned int)f2bf(v0.w) << 16);
  p.z = (unsigned int)f2bf(v1.x) | ((unsigned int)f2bf(v1.y) << 16);
  p.w = (unsigned int)f2bf(v1.z) | ((unsigned int)f2bf(v1.w) << 16);
  ((uint4*)X16)[i] = p;
}

// ---------------- fused RGCN GEMM on matrix cores (unchanged from r12) ----------------
template <int XMODE>
__global__ __launch_bounds__(256) void k_fused(
    const float* __restrict__ X, const unsigned short* __restrict__ X16,
    const unsigned short* __restrict__ Wf, const float* __restrict__ bvec,
    const int* __restrict__ uniq, const int* __restrict__ counter,
    const int* __restrict__ seg_start, const int* __restrict__ s_src,
    float* __restrict__ Hacc) {
  __shared__ __align__(16) unsigned short a_lds[16 * 128];  // 4 KB, swizzled

  int nm = *counter;
  int mid0 = blockIdx.x * 16;
  if (mid0 >= nm) return;

  int t = threadIdx.x;
  int er = t >> 4, seg = t & 15;
  int lane = t & 63, l15 = lane & 15, lg = lane >> 4;
  int wc = t >> 6;
  int mid = mid0 + er;

  f32x4 acc[2];
  {
    f32x4 z = {0.f, 0.f, 0.f, 0.f};
    acc[0] = z; acc[1] = z;
  }

  for (int r = 0; r < 9; ++r) {
    __syncthreads();

    {  // stage A row er chunk seg (8 values)
      float aa[8];
#pragma unroll
      for (int q = 0; q < 8; ++q) aa[q] = 0.f;
      if (r < 8) {
        int comb = mid * 8 + r;
        int s0 = seg_start[comb], s1 = seg_start[comb + 1];
        int cnt = s1 - s0;
        int e = s0;
        if (XMODE == 0) {
          for (; e + 2 <= s1; e += 2) {
            int i0 = s_src[e], i1 = s_src[e + 1];
            const float4* x0 = (const float4*)(X + (size_t)i0 * 128) + seg * 2;
            const float4* x1 = (const float4*)(X + (size_t)i1 * 128) + seg * 2;
            float4 a0 = x0[0], a1 = x0[1], b0 = x1[0], b1 = x1[1];
            aa[0] += a0.x + b0.x; aa[1] += a0.y + b0.y;
            aa[2] += a0.z + b0.z; aa[3] += a0.w + b0.w;
            aa[4] += a1.x + b1.x; aa[5] += a1.y + b1.y;
            aa[6] += a1.z + b1.z; aa[7] += a1.w + b1.w;
          }
          if (e < s1) {
            const float4* x0 = (const float4*)(X + (size_t)s_src[e] * 128) + seg * 2;
            float4 a0 = x0[0], a1 = x0[1];
            aa[0] += a0.x; aa[1] += a0.y; aa[2] += a0.z; aa[3] += a0.w;
            aa[4] += a1.x; aa[5] += a1.y; aa[6] += a1.z; aa[7] += a1.w;
          }
        } else {
          for (; e + 2 <= s1; e += 2) {
            int i0 = s_src[e], i1 = s_src[e + 1];
            uint4 u = *(const uint4*)(X16 + (size_t)i0 * 128 + seg * 8);
            uint4 v = *(const uint4*)(X16 + (size_t)i1 * 128 + seg * 8);
            aa[0] += bflo(u.x) + bflo(v.x); aa[1] += bfhi(u.x) + bfhi(v.x);
            aa[2] += bflo(u.y) + bflo(v.y); aa[3] += bfhi(u.y) + bfhi(v.y);
            aa[4] += bflo(u.z) + bflo(v.z); aa[5] += bfhi(u.z) + bfhi(v.z);
            aa[6] += bflo(u.w) + bflo(v.w); aa[7] += bfhi(u.w) + bfhi(v.w);
          }
          if (e < s1) {
            uint4 u = *(const uint4*)(X16 + (size_t)s_src[e] * 128 + seg * 8);
            aa[0] += bflo(u.x); aa[1] += bfhi(u.x);
            aa[2] += bflo(u.y); aa[3] += bfhi(u.y);
            aa[4] += bflo(u.z); aa[5] += bfhi(u.z);
            aa[6] += bflo(u.w); aa[7] += bfhi(u.w);
          }
        }
        if (cnt > 1) {
          float sc = 1.0f / (float)cnt;
#pragma unroll
          for (int q = 0; q < 8; ++q) aa[q] *= sc;
        }
      } else if (mid < nm) {
        if (XMODE == 0) {
          const float4* xr = (const float4*)(X + (size_t)uniq[mid] * 128) + seg * 2;
          float4 v0 = xr[0], v1 = xr[1];
          aa[0] = v0.x; aa[1] = v0.y; aa[2] = v0.z; aa[3] = v0.w;
          aa[4] = v1.x; aa[5] = v1.y; aa[6] = v1.z; aa[7] = v1.w;
        } else {
          uint4 u = *(const uint4*)(X16 + (size_t)uniq[mid] * 128 + seg * 8);
          aa[0] = bflo(u.x); aa[1] = bfhi(u.x);
          aa[2] = bflo(u.y); aa[3] = bfhi(u.y);
          aa[4] = bflo(u.z); aa[5] = bfhi(u.z);
          aa[6] = bflo(u.w); aa[7] = bfhi(u.w);
        }
      }
      uint4 p;
      p.x = (unsigned int)f2bf(aa[0]) | ((unsigned int)f2bf(aa[1]) << 16);
      p.y = (unsigned int)f2bf(aa[2]) | ((unsigned int)f2bf(aa[3]) << 16);
      p.z = (unsigned int)f2bf(aa[4]) | ((unsigned int)f2bf(aa[5]) << 16);
      p.w = (unsigned int)f2bf(aa[6]) | ((unsigned int)f2bf(aa[7]) << 16);
      *(uint4*)&a_lds[(((er * 16 + seg) ^ (er & 7)) * 8)] = p;
    }
    __syncthreads();

    const unsigned short* wf = Wf + r * 16384;
#pragma unroll
    for (int kb = 0; kb < 4; ++kb) {
      int ku = kb * 4 + lg;
      bf16x8 af = *(const bf16x8*)&a_lds[((l15 * 16 + ku) ^ (l15 & 7)) * 8];
#pragma unroll
      for (int n = 0; n < 2; ++n) {
        int col = wc * 32 + n * 16 + l15;
        bf16x8 bfr = *(const bf16x8*)(wf + ((size_t)(ku * 128 + col)) * 8);
        acc[n] = __builtin_amdgcn_mfma_f32_16x16x32_bf16(af, bfr, acc[n], 0, 0, 0);
      }
    }
  }

#pragma unroll
  for (int n = 0; n < 2; ++n) {
    int col = wc * 32 + n * 16 + l15;
    float bv = bvec[col];
#pragma unroll
    for (int q = 0; q < 4; ++q) {
      int row = mid0 + lg * 4 + q;
      float v = acc[n][q] + bv;
      Hacc[(size_t)row * 128 + col] = v > 0.f ? v : 0.f;
    }
  }
}

// ---------------- DistMult score: one wave per triple ----------------
__global__ void k_score(const float* __restrict__ H, const int* __restrict__ map,
                        const float* __restrict__ rel_emb, const int* __restrict__ tri_nodes,
                        const int* __restrict__ tri_rel, float* __restrict__ out, int B) {
  int w = (blockIdx.x * blockDim.x + threadIdx.x) >> 6;
  int lane = threadIdx.x & 63;
  if (w >= B) return;
  int s = map[tri_nodes[w * 2]];
  int o = map[tri_nodes[w * 2 + 1]];
  const float* hs = H + (size_t)s * 128;
  const float* ho = H + (size_t)o * 128;
  const float* rr = rel_emb + (size_t)tri_rel[w] * 128;
  float p = hs[lane] * ho[lane] * rr[lane] + hs[lane + 64] * ho[lane + 64] * rr[lane + 64];
#pragma unroll
  for (int ofs = 32; ofs > 0; ofs >>= 1) p += __shfl_down(p, ofs);
  if (lane == 0) out[w] = p;
}

extern "C" void kernel_launch(void* const* d_in, const int* in_sizes, int n_in,
                              void* d_out, int out_size, void* d_ws, size_t ws_size,
                              hipStream_t stream) {
  const float* X       = (const float*)d_in[0];
  const float* W_rel   = (const float*)d_in[1];
  const float* W_self  = (const float*)d_in[2];
  const float* bvec    = (const float*)d_in[3];
  const float* rel_emb = (const float*)d_in[4];
  const int* edge_src  = (const int*)d_in[5];
  const int* edge_dst  = (const int*)d_in[6];
  const int* edge_rel  = (const int*)d_in[7];
  const int* tri_nodes = (const int*)d_in[8];
  const int* tri_rel   = (const int*)d_in[9];

  int N  = in_sizes[0] / 128;   // 100000
  int E  = in_sizes[5];         // 1600000
  int nt = in_sizes[8];         // 2*B = 32768
  int B  = in_sizes[9];         // 16384
  int M  = nt * 8;              // 262144 combs

  char* ws = (char*)d_ws;
  int* map       = (int*)ws;                 // N
  int* counter   = map + N;                  // [0]=nm, [1]=ec (+pad 64)
  int* uniq      = counter + 64;             // nt
  int* cnt_c     = uniq + nt;                // M  (reused as Wf after scan_s3)
  int* seg_start = cnt_c + M;                // M+1 (+pad 64)
  int* seg_ofs   = seg_start + M + 64;       // M
  int* bsum      = seg_ofs + M;              // 256
  int* s_src     = bsum + 256;               // E
  float* Hacc    = (float*)(s_src + E);      // nt*128 floats
  unsigned short* Wf  = (unsigned short*)cnt_c;  // aliases dead cnt_c
  unsigned short* X16 = (unsigned short*)(Hacc + (size_t)nt * 128);  // N*128 bf16
  size_t need_big = ((char*)(X16 + (size_t)N * 128)) - ws;  // ~52.5 MB (proven r12)
  bool bigws = ws_size >= need_big;
  // c_pk (E int2 = 12.8 MB) aliases X16 (written later) in bigws mode, else Hacc.
  int2* c_pk = bigws ? (int2*)X16 : (int2*)Hacc;

  hipMemsetAsync(map, 0xFF, (size_t)N * 4, stream);  // -1
  hipMemsetAsync(counter, 0, 64 * 4, stream);
  hipMemsetAsync(cnt_c, 0, (size_t)M * 4, stream);

  int eblocks = (E + 255) / 256;
  k_build_map<<<(nt + 255) / 256, 256, 0, stream>>>(tri_nodes, map, uniq, counter, nt);
  k_compact<<<eblocks, 256, 0, stream>>>(edge_src, edge_dst, edge_rel, map, cnt_c,
                                         counter + 1, c_pk, E);
  k_scan_s1<<<256, 256, 0, stream>>>(cnt_c, bsum);
  k_scan_s2<<<1, 256, 0, stream>>>(bsum, seg_start, M);
  k_scan_s3<<<256, 256, 0, stream>>>(cnt_c, bsum, seg_start, seg_ofs);
  // cnt_c dead from here; overwrite with bf16 fragment-major weights
  k_cvt_w<<<(9 * 16384 + 255) / 256, 256, 0, stream>>>(W_rel, W_self, Wf);
  k_scatter2<<<eblocks, 256, 0, stream>>>(c_pk, counter + 1, seg_ofs, s_src);
  // c_pk dead from here
  if (bigws) {
    k_cvt_x<<<(N * 16 + 255) / 256, 256, 0, stream>>>(X, X16, N * 16);
    k_fused<1><<<nt / 16, 256, 0, stream>>>(X, X16, Wf, bvec, uniq, counter,
                                            seg_start, s_src, Hacc);
  } else {
    k_fused<0><<<nt / 16, 256, 0, stream>>>(X, X16, Wf, bvec, uniq, counter,
                                            seg_start, s_src, Hacc);
  }
  k_score<<<(B * 64 + 255) / 256, 256, 0, stream>>>(Hacc, map, rel_emb, tri_nodes,
                                                    tri_rel, (float*)d_out, B);
}

// Round 15
// 132.927 us; speedup vs baseline: 3.0879x; 1.4653x over previous
//
#include <hip/hip_runtime.h>

typedef float f32x4 __attribute__((ext_vector_type(4)));
typedef short bf16x8 __attribute__((ext_vector_type(8)));

__device__ __forceinline__ unsigned short f2bf(float f) {
  unsigned int u = __float_as_uint(f);
  u += 0x7FFFu + ((u >> 16) & 1u);  // RNE
  return (unsigned short)(u >> 16);
}
__device__ __forceinline__ float bflo(unsigned int u) {  // low bf16 -> f32
  return __uint_as_float(u << 16);
}
__device__ __forceinline__ float bfhi(unsigned int u) {  // high bf16 -> f32
  return __uint_as_float(u & 0xFFFF0000u);
}

// ---------------- build node -> compact id map ----------------
__global__ void k_build_map(const int* __restrict__ tri_nodes, int* __restrict__ map,
                            int* __restrict__ uniq, int* __restrict__ counter, int n) {
  int i = blockIdx.x * blockDim.x + threadIdx.x;
  if (i >= n) return;
  int node = tri_nodes[i];
  int old = atomicCAS(&map[node], -1, -2);
  if (old == -1) {
    int mid = atomicAdd(counter, 1);
    uniq[mid] = node;
    map[node] = mid;
  }
}

// ---------------- count needed edges per comb = mid*8+rel ----------------
__global__ void k_count(const int* __restrict__ edst, const int* __restrict__ erel,
                        const int* __restrict__ map, int* __restrict__ cnt_c, int E) {
  int i = blockIdx.x * blockDim.x + threadIdx.x;
  if (i >= E) return;
  int mid = map[edst[i]];
  if (mid >= 0) atomicAdd(&cnt_c[mid * 8 + erel[i]], 1);
}

// ---------------- hierarchical exclusive scan over M=262144 entries ----------------
__global__ __launch_bounds__(256) void k_scan_s1(const int* __restrict__ cnt_c,
                                                 int* __restrict__ bsum) {
  __shared__ int sh[256];
  int tid = threadIdx.x;
  int base = blockIdx.x * 1024 + tid * 4;
  int s = cnt_c[base] + cnt_c[base + 1] + cnt_c[base + 2] + cnt_c[base + 3];
  sh[tid] = s;
  __syncthreads();
  for (int o = 1; o < 256; o <<= 1) {
    int x = (tid >= o) ? sh[tid - o] : 0;
    __syncthreads();
    sh[tid] += x;
    __syncthreads();
  }
  if (tid == 255) bsum[blockIdx.x] = sh[255];
}
__global__ __launch_bounds__(256) void k_scan_s2(int* __restrict__ bsum,
                                                 int* __restrict__ seg_start, int M) {
  __shared__ int sh[256];
  int tid = threadIdx.x;
  int v = bsum[tid];
  sh[tid] = v;
  __syncthreads();
  for (int o = 1; o < 256; o <<= 1) {
    int x = (tid >= o) ? sh[tid - o] : 0;
    __syncthreads();
    sh[tid] += x;
    __syncthreads();
  }
  bsum[tid] = sh[tid] - v;  // exclusive
  if (tid == 255) seg_start[M] = sh[255];
}
__global__ __launch_bounds__(256) void k_scan_s3(const int* __restrict__ cnt_c,
                                                 const int* __restrict__ bsum,
                                                 int* __restrict__ seg_start,
                                                 int* __restrict__ seg_ofs) {
  __shared__ int sh[256];
  int tid = threadIdx.x;
  int base = blockIdx.x * 1024 + tid * 4;
  int c0 = cnt_c[base], c1 = cnt_c[base + 1], c2 = cnt_c[base + 2], c3 = cnt_c[base + 3];
  int s = c0 + c1 + c2 + c3;
  sh[tid] = s;
  __syncthreads();
  for (int o = 1; o < 256; o <<= 1) {
    int x = (tid >= o) ? sh[tid - o] : 0;
    __syncthreads();
    sh[tid] += x;
    __syncthreads();
  }
  int run = bsum[blockIdx.x] + sh[tid] - s;
  seg_start[base] = run; seg_ofs[base] = run; run += c0;
  seg_start[base + 1] = run; seg_ofs[base + 1] = run; run += c1;
  seg_start[base + 2] = run; seg_ofs[base + 2] = run; run += c2;
  seg_start[base + 3] = run; seg_ofs[base + 3] = run;
}

// ---------------- scatter needed edge srcs into comb-sorted order ----------------
__global__ void k_scatter(const int* __restrict__ esrc, const int* __restrict__ edst,
                          const int* __restrict__ erel, const int* __restrict__ map,
                          int* __restrict__ seg_ofs, int* __restrict__ s_src, int E) {
  int i = blockIdx.x * blockDim.x + threadIdx.x;
  if (i >= E) return;
  int mid = map[edst[i]];
  if (mid >= 0) {
    int comb = mid * 8 + erel[i];
    int pos = atomicAdd(&seg_ofs[comb], 1);
    s_src[pos] = esrc[i];
  }
}

// ---------------- W -> bf16 FRAGMENT-MAJOR: Wf[((r*16+ku)*128+col)*8+j] = W[r][ku*8+j][col]
__global__ void k_cvt_w(const float* __restrict__ W_rel, const float* __restrict__ W_self,
                        unsigned short* __restrict__ Wf) {
  int i = blockIdx.x * 256 + threadIdx.x;  // over 9*16384 bf16 elements
  if (i >= 9 * 16384) return;
  int j = i & 7;
  int tmp = i >> 3;
  int col = tmp & 127;
  int ku = (tmp >> 7) & 15;
  int r = tmp >> 11;
  int d = ku * 8 + j;
  float v = (r < 8) ? W_rel[r * 16384 + d * 128 + col] : W_self[d * 128 + col];
  Wf[i] = f2bf(v);
}

// ---------------- X -> bf16 (ws-gated): halves gather bytes ----------------
__global__ void k_cvt_x(const float* __restrict__ X, unsigned short* __restrict__ X16,
                        int total8) {
  int i = blockIdx.x * 256 + threadIdx.x;  // one thread per 8 elements
  if (i >= total8) return;
  const float4* s = (const float4*)(X + (size_t)i * 8);
  float4 v0 = s[0], v1 = s[1];
  uint4 p;
  p.x = (unsigned int)f2bf(v0.x) | ((unsigned int)f2bf(v0.y) << 16);
  p.y = (unsigned int)f2bf(v0.z) | ((unsigned int)f2bf(v0.w) << 16);
  p.z = (unsigned int)f2bf(v1.x) | ((unsigned int)f2bf(v1.y) << 16);
  p.w = (unsigned int)f2bf(v1.z) | ((unsigned int)f2bf(v1.w) << 16);
  ((uint4*)X16)[i] = p;
}

// ---------------- fused RGCN GEMM on matrix cores ----------------
// r12 structure + ONE change: the block's contiguous s_src index range
// [seg_start[mid0*8], seg_start[mid0*8+128]) is staged into LDS once
// (coalesced), removing the per-edge global s_src load from the gather's
// dependent chain. Uniform fallback to the global path if range > 768.
template <int XMODE>
__global__ __launch_bounds__(256) void k_fused(
    const float* __restrict__ X, const unsigned short* __restrict__ X16,
    const unsigned short* __restrict__ Wf, const float* __restrict__ bvec,
    const int* __restrict__ uniq, const int* __restrict__ counter,
    const int* __restrict__ seg_start, const int* __restrict__ s_src,
    float* __restrict__ Hacc) {
  __shared__ __align__(16) unsigned short a_lds[16 * 128];  // 4 KB, swizzled
  __shared__ int lds_src[768];                              // 3 KB index stage

  int nm = *counter;
  int mid0 = blockIdx.x * 16;
  if (mid0 >= nm) return;

  int t = threadIdx.x;
  int er = t >> 4, seg = t & 15;
  int lane = t & 63, l15 = lane & 15, lg = lane >> 4;
  int wc = t >> 6;
  int mid = mid0 + er;

  // stage this block's edge-index range (contiguous in comb-sorted order)
  int i0 = seg_start[mid0 * 8];
  int range = seg_start[mid0 * 8 + 128] - i0;
  for (int j = t; j < range && j < 768; j += 256) lds_src[j] = s_src[i0 + j];
  bool fits = (range <= 768);  // block-uniform

  f32x4 acc[2];
  {
    f32x4 z = {0.f, 0.f, 0.f, 0.f};
    acc[0] = z; acc[1] = z;
  }

  for (int r = 0; r < 9; ++r) {
    __syncthreads();  // orders staging (r=0) / prev MFMA before a_lds overwrite

    {  // stage A row er chunk seg (8 values)
      float aa[8];
#pragma unroll
      for (int q = 0; q < 8; ++q) aa[q] = 0.f;

      auto addrow = [&](int sidx) {
        if (XMODE == 0) {
          const float4* xr = (const float4*)(X + (size_t)sidx * 128) + seg * 2;
          float4 v0 = xr[0], v1 = xr[1];
          aa[0] += v0.x; aa[1] += v0.y; aa[2] += v0.z; aa[3] += v0.w;
          aa[4] += v1.x; aa[5] += v1.y; aa[6] += v1.z; aa[7] += v1.w;
        } else {
          uint4 u = *(const uint4*)(X16 + (size_t)sidx * 128 + seg * 8);
          aa[0] += bflo(u.x); aa[1] += bfhi(u.x);
          aa[2] += bflo(u.y); aa[3] += bfhi(u.y);
          aa[4] += bflo(u.z); aa[5] += bfhi(u.z);
          aa[6] += bflo(u.w); aa[7] += bfhi(u.w);
        }
      };

      if (r < 8) {
        int comb = mid * 8 + r;
        int s0 = seg_start[comb], s1 = seg_start[comb + 1];
        int cnt = s1 - s0;
        if (fits) {  // indices from LDS: chain = X16 load only
          int o = s0 - i0, oe = s1 - i0;
          for (; o + 2 <= oe; o += 2) {
            int ia = lds_src[o], ib = lds_src[o + 1];
            addrow(ia);
            addrow(ib);
          }
          if (o < oe) addrow(lds_src[o]);
        } else {     // rare fallback: original global path
          int e = s0;
          for (; e + 2 <= s1; e += 2) {
            int ia = s_src[e], ib = s_src[e + 1];
            addrow(ia);
            addrow(ib);
          }
          if (e < s1) addrow(s_src[e]);
        }
        if (cnt > 1) {
          float sc = 1.0f / (float)cnt;
#pragma unroll
          for (int q = 0; q < 8; ++q) aa[q] *= sc;
        }
      } else if (mid < nm) {
        addrow(uniq[mid]);
      }
      uint4 p;
      p.x = (unsigned int)f2bf(aa[0]) | ((unsigned int)f2bf(aa[1]) << 16);
      p.y = (unsigned int)f2bf(aa[2]) | ((unsigned int)f2bf(aa[3]) << 16);
      p.z = (unsigned int)f2bf(aa[4]) | ((unsigned int)f2bf(aa[5]) << 16);
      p.w = (unsigned int)f2bf(aa[6]) | ((unsigned int)f2bf(aa[7]) << 16);
      *(uint4*)&a_lds[(((er * 16 + seg) ^ (er & 7)) * 8)] = p;
    }
    __syncthreads();  // a_lds ready

    const unsigned short* wf = Wf + r * 16384;
#pragma unroll
    for (int kb = 0; kb < 4; ++kb) {
      int ku = kb * 4 + lg;
      bf16x8 af = *(const bf16x8*)&a_lds[((l15 * 16 + ku) ^ (l15 & 7)) * 8];
#pragma unroll
      for (int n = 0; n < 2; ++n) {
        int col = wc * 32 + n * 16 + l15;
        bf16x8 bfr = *(const bf16x8*)(wf + ((size_t)(ku * 128 + col)) * 8);
        acc[n] = __builtin_amdgcn_mfma_f32_16x16x32_bf16(af, bfr, acc[n], 0, 0, 0);
      }
    }
  }

  // epilogue: bias + relu, plain stores. C/D map: col=lane&15, row=(lane>>4)*4+reg
#pragma unroll
  for (int n = 0; n < 2; ++n) {
    int col = wc * 32 + n * 16 + l15;
    float bv = bvec[col];
#pragma unroll
    for (int q = 0; q < 4; ++q) {
      int row = mid0 + lg * 4 + q;
      float v = acc[n][q] + bv;
      Hacc[(size_t)row * 128 + col] = v > 0.f ? v : 0.f;
    }
  }
}

// ---------------- DistMult score: one wave per triple ----------------
__global__ void k_score(const float* __restrict__ H, const int* __restrict__ map,
                        const float* __restrict__ rel_emb, const int* __restrict__ tri_nodes,
                        const int* __restrict__ tri_rel, float* __restrict__ out, int B) {
  int w = (blockIdx.x * blockDim.x + threadIdx.x) >> 6;
  int lane = threadIdx.x & 63;
  if (w >= B) return;
  int s = map[tri_nodes[w * 2]];
  int o = map[tri_nodes[w * 2 + 1]];
  const float* hs = H + (size_t)s * 128;
  const float* ho = H + (size_t)o * 128;
  const float* rr = rel_emb + (size_t)tri_rel[w] * 128;
  float p = hs[lane] * ho[lane] * rr[lane] + hs[lane + 64] * ho[lane + 64] * rr[lane + 64];
#pragma unroll
  for (int ofs = 32; ofs > 0; ofs >>= 1) p += __shfl_down(p, ofs);
  if (lane == 0) out[w] = p;
}

extern "C" void kernel_launch(void* const* d_in, const int* in_sizes, int n_in,
                              void* d_out, int out_size, void* d_ws, size_t ws_size,
                              hipStream_t stream) {
  const float* X       = (const float*)d_in[0];
  const float* W_rel   = (const float*)d_in[1];
  const float* W_self  = (const float*)d_in[2];
  const float* bvec    = (const float*)d_in[3];
  const float* rel_emb = (const float*)d_in[4];
  const int* edge_src  = (const int*)d_in[5];
  const int* edge_dst  = (const int*)d_in[6];
  const int* edge_rel  = (const int*)d_in[7];
  const int* tri_nodes = (const int*)d_in[8];
  const int* tri_rel   = (const int*)d_in[9];

  int N  = in_sizes[0] / 128;   // 100000
  int E  = in_sizes[5];         // 1600000
  int nt = in_sizes[8];         // 2*B = 32768
  int B  = in_sizes[9];         // 16384
  int M  = nt * 8;              // 262144 combs

  char* ws = (char*)d_ws;
  int* map       = (int*)ws;                 // N
  int* counter   = map + N;                  // 1 (+pad 64)
  int* uniq      = counter + 64;             // nt
  int* cnt_c     = uniq + nt;                // M  (reused as Wf after scan_s3)
  int* seg_start = cnt_c + M;                // M+1 (+pad 64)
  int* seg_ofs   = seg_start + M + 64;       // M
  int* bsum      = seg_ofs + M;              // 256
  int* s_src     = bsum + 256;               // E
  float* Hacc    = (float*)(s_src + E);      // nt*128 floats
  unsigned short* Wf  = (unsigned short*)cnt_c;  // aliases dead cnt_c
  unsigned short* X16 = (unsigned short*)(Hacc + (size_t)nt * 128);  // N*128 bf16
  size_t need_big = ((char*)(X16 + (size_t)N * 128)) - ws;  // ~52.5 MB (proven r12)
  bool bigws = ws_size >= need_big;

  hipMemsetAsync(map, 0xFF, (size_t)N * 4, stream);  // -1
  hipMemsetAsync(counter, 0, 64 * 4, stream);
  hipMemsetAsync(cnt_c, 0, (size_t)M * 4, stream);

  int eblocks = (E + 255) / 256;  // one thread per edge
  k_build_map<<<(nt + 255) / 256, 256, 0, stream>>>(tri_nodes, map, uniq, counter, nt);
  k_count<<<eblocks, 256, 0, stream>>>(edge_dst, edge_rel, map, cnt_c, E);
  k_scan_s1<<<256, 256, 0, stream>>>(cnt_c, bsum);
  k_scan_s2<<<1, 256, 0, stream>>>(bsum, seg_start, M);
  k_scan_s3<<<256, 256, 0, stream>>>(cnt_c, bsum, seg_start, seg_ofs);
  // cnt_c dead from here; overwrite with bf16 fragment-major weights
  k_cvt_w<<<(9 * 16384 + 255) / 256, 256, 0, stream>>>(W_rel, W_self, Wf);
  k_scatter<<<eblocks, 256, 0, stream>>>(edge_src, edge_dst, edge_rel, map, seg_ofs,
                                         s_src, E);
  if (bigws) {
    k_cvt_x<<<(N * 16 + 255) / 256, 256, 0, stream>>>(X, X16, N * 16);
    k_fused<1><<<nt / 16, 256, 0, stream>>>(X, X16, Wf, bvec, uniq, counter,
                                            seg_start, s_src, Hacc);
  } else {
    k_fused<0><<<nt / 16, 256, 0, stream>>>(X, X16, Wf, bvec, uniq, counter,
                                            seg_start, s_src, Hacc);
  }
  k_score<<<(B * 64 + 255) / 256, 256, 0, stream>>>(Hacc, map, rel_emb, tri_nodes,
                                                    tri_rel, (float*)d_out, B);
}